// Round 2
// baseline (3168.944 us; speedup 1.0000x reference)
//
#include <hip/hip_runtime.h>
#include <stdint.h>

#define N_TOK 8192
#define DIM   2048
#define NEXP  16
#define HID   1408
#define SHID  2816
#define KTOP  4

typedef __attribute__((ext_vector_type(8))) short bf16x8;
typedef __attribute__((ext_vector_type(4))) float f32x4;

#define MFMA16(a,b,c) __builtin_amdgcn_mfma_f32_16x16x32_bf16((a),(b),(c),0,0,0)

__device__ __forceinline__ unsigned short f2b(float f){
  unsigned u = __float_as_uint(f);
  return (unsigned short)((u + 0x7fffu + ((u >> 16) & 1u)) >> 16);  // RNE bf16
}
__device__ __forceinline__ unsigned pk2(float a, float b){
  return (unsigned)f2b(a) | ((unsigned)f2b(b) << 16);
}
__device__ __forceinline__ float bu2f(unsigned hs){ return __uint_as_float(hs << 16); }
__device__ __forceinline__ float siluf(float x){ return x / (1.f + expf(-x)); }
__device__ __forceinline__ f32x4 zero4(){ f32x4 z; z[0]=0.f; z[1]=0.f; z[2]=0.f; z[3]=0.f; return z; }

// async global->LDS, 16B per lane. LDS dest is wave-uniform base + lane*16 (linear).
__device__ __forceinline__ void gll16(const unsigned short* g, unsigned short* l){
  __builtin_amdgcn_global_load_lds(
      (const __attribute__((address_space(1))) void*)g,
      (__attribute__((address_space(3))) void*)l, 16, 0, 0);
}

// ---------------- fp32 -> bf16 convert (vectorized) ----------------
__global__ __launch_bounds__(256) void k_cvt(const float* __restrict__ s,
                                             unsigned short* __restrict__ d, size_t n4){
  size_t i = (size_t)blockIdx.x*256 + threadIdx.x;
  size_t st = (size_t)gridDim.x*256;
  for (; i < n4; i += st){
    float4 v = ((const float4*)s)[i];
    uint2 q; q.x = pk2(v.x, v.y); q.y = pk2(v.z, v.w);
    ((uint2*)d)[i] = q;
  }
}

// ---------------- gate: fp32 logits, softmax, top-4 (wave per token) ----------------
__global__ __launch_bounds__(256) void k_gate(const float* __restrict__ X, const float* __restrict__ Wg,
                                              float* __restrict__ topw, int* __restrict__ topi,
                                              int* __restrict__ cnt){
  int lane = threadIdx.x & 63;
  int t = blockIdx.x*4 + (threadIdx.x >> 6);
  const float* xr = X + (size_t)t*DIM;
  float xv[32];
#pragma unroll
  for (int i=0;i<32;i++) xv[i] = xr[i*64 + lane];
  float sc[NEXP];
#pragma unroll
  for (int e=0;e<NEXP;e++){
    const float* wr = Wg + e*DIM;
    float s = 0.f;
#pragma unroll
    for (int i=0;i<32;i++) s = fmaf(xv[i], wr[i*64 + lane], s);
#pragma unroll
    for (int d=1; d<64; d<<=1) s += __shfl_xor(s, d);
    sc[e] = s;
  }
  if (lane == 0){
    float m = sc[0];
#pragma unroll
    for (int e=1;e<NEXP;e++) m = fmaxf(m, sc[e]);
    float den = 0.f;
#pragma unroll
    for (int e=0;e<NEXP;e++){ sc[e] = expf(sc[e]-m); den += sc[e]; }
    float inv = 1.f/den;
#pragma unroll
    for (int e=0;e<NEXP;e++) sc[e] *= inv;
    for (int k=0;k<KTOP;k++){
      int bi = 0; float bv = sc[0];
#pragma unroll
      for (int e=1;e<NEXP;e++) if (sc[e] > bv){ bv = sc[e]; bi = e; }
      topw[t*KTOP+k] = bv;           // ROUTE_SCALE == 1
      topi[t*KTOP+k] = bi;
#pragma unroll
      for (int e=0;e<NEXP;e++) if (e == bi) sc[e] = -1.f;   // static-index kill
      atomicAdd(&cnt[bi], 1);
    }
  }
}

__global__ void k_scan(const int* __restrict__ cnt, int* __restrict__ off, int* __restrict__ cur){
  if (threadIdx.x == 0){
    int a = 0;
    for (int e=0;e<NEXP;e++){ off[e] = a; cur[e] = a; a += cnt[e]; }
  }
}

__global__ __launch_bounds__(256) void k_place(const int* __restrict__ topi, const float* __restrict__ topw,
                                               int* __restrict__ cur, int* __restrict__ rows,
                                               float* __restrict__ rw, int* __restrict__ slotL){
  int t = blockIdx.x*256 + threadIdx.x;
#pragma unroll
  for (int k=0;k<KTOP;k++){
    int e = topi[t*KTOP+k];
    int p = atomicAdd(&cur[e], 1);
    rows[p] = t;
    rw[p]   = topw[t*KTOP+k];
    slotL[t*KTOP+k] = p;
  }
}

// fp32-weight fallback staging (reg-staged, writes the same swizzled layout)
__device__ __forceinline__ void stage_Bf(unsigned short* lsB, const float* bF,
                                         int ldK, int bn0, int k0, int tid){
#pragma unroll
  for (int j=0;j<8;j++){
    int idx = j*256 + tid, r = idx >> 4, c4 = idx & 15;
    float4 v = *(const float4*)(bF + (size_t)(bn0 + r)*ldK + k0 + c4*4);
    uint2 q; q.x = pk2(v.x, v.y); q.y = pk2(v.z, v.w);
    *(uint2*)&lsB[r*64 + (((c4 >> 1) ^ (r & 7)) << 3) + ((c4 & 1) << 2)] = q;
  }
}

__device__ __forceinline__ void read_A(bf16x8 af[4], const unsigned short* lsA, int wm, int lane, int kc){
  int s = kc*4 + (lane >> 4);
#pragma unroll
  for (int mi=0;mi<4;mi++){
    int r = wm + mi*16 + (lane & 15);
    af[mi] = *(const bf16x8*)&lsA[r*64 + ((s ^ (r & 7)) << 3)];
  }
}

// ---------------- routed up+gate proj: H1 = silu(A@W1^T+b1)*(A@W3^T+b3), gathered rows ----------------
// 128x128x64 tile, 4 waves. Staging: global_load_lds w=16, linear LDS dest,
// source k-chunk pre-XOR'd (c = (l&7)^((l>>3)&7)) to match read-side swizzle.
template<bool WBF>
__global__ __launch_bounds__(256) void k_g13(const unsigned short* __restrict__ Xb,
    const void* __restrict__ W1p, const void* __restrict__ W3p,
    const float* __restrict__ b1, const float* __restrict__ b3,
    const int* __restrict__ rows, const int* __restrict__ cnt, const int* __restrict__ offs,
    unsigned short* __restrict__ H1)
{
  int e = blockIdx.y;
  int ct = blockIdx.x >> 6, rt = blockIdx.x & 63;
  int cntE = cnt[e];
  if (rt*128 >= cntE) return;
  int offE = offs[e];
  int hn0 = ct*128;
  int tid = threadIdx.x, lane = tid & 63, wid = tid >> 6;
  int wm = (wid >> 1)*64, wn = (wid & 1)*64;
  __shared__ alignas(16) unsigned short lsA[8192], lsB1[8192], lsB3[8192];

  int lr8 = lane >> 3;            // row within 8-row group
  int cx  = (lane & 7) ^ lr8;     // pre-swizzled source k-chunk (involution of read XOR)
  unsigned offA[4], offB[4];
#pragma unroll
  for (int j=0;j<4;j++){
    int r = wid*32 + j*8 + lr8;   // r&7 == lr8
    int lrow = rt*128 + r;
    int arow = rows[offE + (lrow < cntE ? lrow : cntE-1)];
    offA[j] = (unsigned)arow*DIM + (unsigned)cx*8;
    offB[j] = (unsigned)(hn0 + r)*DIM + (unsigned)cx*8;
  }
  const unsigned short* b1H = (const unsigned short*)W1p + (size_t)e*HID*DIM;
  const unsigned short* b3H = (const unsigned short*)W3p + (size_t)e*HID*DIM;
  const float* b1F = (const float*)W1p + (size_t)e*HID*DIM;
  const float* b3F = (const float*)W3p + (size_t)e*HID*DIM;
  unsigned short* lA  = &lsA[wid*2048];
  unsigned short* lB1 = &lsB1[wid*2048];
  unsigned short* lB3 = &lsB3[wid*2048];

  f32x4 acc1[4][4], acc3[4][4];
#pragma unroll
  for (int i=0;i<4;i++)
#pragma unroll
    for (int j=0;j<4;j++){ acc1[i][j] = zero4(); acc3[i][j] = zero4(); }

  for (int kt=0; kt<DIM/64; ++kt){
    int k0 = kt*64;
    __syncthreads();
#pragma unroll
    for (int j=0;j<4;j++){
      gll16(Xb + offA[j] + k0, lA + j*512);
      if constexpr (WBF){
        gll16(b1H + offB[j] + k0, lB1 + j*512);
        gll16(b3H + offB[j] + k0, lB3 + j*512);
      }
    }
    if constexpr (!WBF){
      stage_Bf(lsB1, b1F, DIM, hn0, k0, tid);
      stage_Bf(lsB3, b3F, DIM, hn0, k0, tid);
    }
    __syncthreads();   // compiler drains vmcnt/lgkmcnt here -> staged data visible
#pragma unroll
    for (int kc=0;kc<2;kc++){
      bf16x8 af[4]; read_A(af, lsA, wm, lane, kc);
      int sB = kc*4 + (lane >> 4);
#pragma unroll
      for (int nj=0;nj<4;nj++){
        int rb = wn + nj*16 + (lane & 15);
        int lof = rb*64 + ((sB ^ (rb & 7)) << 3);
        bf16x8 bf1 = *(const bf16x8*)&lsB1[lof];
        bf16x8 bf3 = *(const bf16x8*)&lsB3[lof];
#pragma unroll
        for (int mi=0;mi<4;mi++){
          acc1[mi][nj] = MFMA16(af[mi], bf1, acc1[mi][nj]);
          acc3[mi][nj] = MFMA16(af[mi], bf3, acc3[mi][nj]);
        }
      }
    }
  }
#pragma unroll
  for (int nj=0;nj<4;nj++){
    int h = hn0 + wn + nj*16 + (lane & 15);
    float b1v = b1[e*HID + h];
    float b3v = b3[e*HID + h];
#pragma unroll
    for (int mi=0;mi<4;mi++){
#pragma unroll
      for (int r=0;r<4;r++){
        int gr = rt*128 + wm + mi*16 + (lane >> 4)*4 + r;
        if (gr < cntE){
          float u = acc1[mi][nj][r] + b1v;
          float v = acc3[mi][nj][r] + b3v;
          H1[(size_t)(offE + gr)*HID + h] = f2b(siluf(u)*v);
        }
      }
    }
  }
}

// ---------------- generic single-B GEMM: MODE 0=gs1(silu->Hs) 1=gs2(store out) 2=g2 atomic 3=g2->Yrows ----------------
template<int MODE, bool WBF, int KSTEPS>
__global__ __launch_bounds__(256) void k_gemm(const unsigned short* __restrict__ Abase,
    const void* __restrict__ Bpv, const float* __restrict__ bias,
    float* __restrict__ outF, unsigned short* __restrict__ outH,
    const int* __restrict__ rows, const float* __restrict__ rw,
    const int* __restrict__ cnt, const int* __restrict__ offs)
{
  constexpr int KD = KSTEPS*64;
  int e = 0;
  if constexpr (MODE >= 2) e = blockIdx.y;
  int ct = blockIdx.x >> 6, rt = blockIdx.x & 63;
  int cntE = 0, offE = 0;
  if constexpr (MODE >= 2){
    cntE = cnt[e];
    if (rt*128 >= cntE) return;
    offE = offs[e];
  }
  int bn0 = ct*128, t0 = rt*128;
  int tid = threadIdx.x, lane = tid & 63, wid = tid >> 6;
  int wm = (wid >> 1)*64, wn = (wid & 1)*64;
  __shared__ alignas(16) unsigned short lsA[8192], lsB[8192];

  int lr8 = lane >> 3;
  int cx  = (lane & 7) ^ lr8;
  unsigned offA[4], offB[4];
#pragma unroll
  for (int j=0;j<4;j++){
    int r = wid*32 + j*8 + lr8;
    int arow;
    if constexpr (MODE >= 2){
      int lrow = t0 + r;
      arow = offE + (lrow < cntE ? lrow : cntE-1);
    } else arow = t0 + r;
    offA[j] = (unsigned)arow*KD + (unsigned)cx*8;
    offB[j] = (unsigned)(bn0 + r)*KD + (unsigned)cx*8;
  }
  const unsigned short* bH = (const unsigned short*)Bpv + ((MODE >= 2) ? (size_t)e*2048*KD : (size_t)0);
  const float*          bF = (const float*)Bpv          + ((MODE >= 2) ? (size_t)e*2048*KD : (size_t)0);
  const float* biasp = bias + ((MODE >= 2) ? e*DIM : 0);
  unsigned short* lA = &lsA[wid*2048];
  unsigned short* lB = &lsB[wid*2048];

  f32x4 acc[4][4];
#pragma unroll
  for (int i=0;i<4;i++)
#pragma unroll
    for (int j=0;j<4;j++) acc[i][j] = zero4();

  for (int kt=0; kt<KSTEPS; ++kt){
    int k0 = kt*64;
    __syncthreads();
#pragma unroll
    for (int j=0;j<4;j++){
      gll16(Abase + offA[j] + k0, lA + j*512);
      if constexpr (WBF) gll16(bH + offB[j] + k0, lB + j*512);
    }
    if constexpr (!WBF) stage_Bf(lsB, bF, KD, bn0, k0, tid);
    __syncthreads();
#pragma unroll
    for (int kc=0;kc<2;kc++){
      bf16x8 af[4]; read_A(af, lsA, wm, lane, kc);
      int sB = kc*4 + (lane >> 4);
#pragma unroll
      for (int nj=0;nj<4;nj++){
        int rb = wn + nj*16 + (lane & 15);
        bf16x8 bfr = *(const bf16x8*)&lsB[rb*64 + ((sB ^ (rb & 7)) << 3)];
#pragma unroll
        for (int mi=0;mi<4;mi++)
          acc[mi][nj] = MFMA16(af[mi], bfr, acc[mi][nj]);
      }
    }
  }
#pragma unroll
  for (int nj=0;nj<4;nj++){
    int col = bn0 + wn + nj*16 + (lane & 15);
    float bv = biasp[col];
#pragma unroll
    for (int mi=0;mi<4;mi++){
#pragma unroll
      for (int r=0;r<4;r++){
        int lr = wm + mi*16 + (lane >> 4)*4 + r;
        float v = acc[mi][nj][r] + bv;
        if constexpr (MODE == 0){
          outH[(size_t)(t0 + lr)*SHID + col] = f2b(siluf(v));
        } else if constexpr (MODE == 1){
          outF[(size_t)(t0 + lr)*DIM + col] = v;
        } else {
          int gr = t0 + lr;
          if (gr < cntE){
            int slot = offE + gr;
            float wv = rw[slot] * v;
            if constexpr (MODE == 2){
              atomicAdd(outF + (size_t)rows[slot]*DIM + col, wv);
            } else {
              outH[(size_t)slot*DIM + col] = f2b(wv);
            }
          }
        }
      }
    }
  }
}

// ---------------- deterministic combine: out += sum_k Yrows[slot(t,k)] ----------------
__global__ __launch_bounds__(256) void k_comb(const unsigned short* __restrict__ Yr,
                                              const int* __restrict__ slotL, float* __restrict__ out){
  int i = blockIdx.x*256 + threadIdx.x;
  int t = i >> 8, c = i & 255;
  size_t ob = (size_t)t*DIM + (size_t)c*8;
  float4 a = *(float4*)(out + ob);
  float4 b = *(float4*)(out + ob + 4);
  int sl[4];
#pragma unroll
  for (int k=0;k<KTOP;k++) sl[k] = slotL[t*KTOP + k];
#pragma unroll
  for (int k=0;k<KTOP;k++){
    uint4 v = *(const uint4*)(Yr + (size_t)sl[k]*DIM + (size_t)c*8);
    a.x += bu2f(v.x & 0xffffu); a.y += bu2f(v.x >> 16);
    a.z += bu2f(v.y & 0xffffu); a.w += bu2f(v.y >> 16);
    b.x += bu2f(v.z & 0xffffu); b.y += bu2f(v.z >> 16);
    b.z += bu2f(v.w & 0xffffu); b.w += bu2f(v.w >> 16);
  }
  *(float4*)(out + ob) = a;
  *(float4*)(out + ob + 4) = b;
}

// ---------------- host ----------------
extern "C" void kernel_launch(void* const* d_in, const int* in_sizes, int n_in,
                              void* d_out, int out_size, void* d_ws, size_t ws_size,
                              hipStream_t stream)
{
  (void)in_sizes; (void)n_in; (void)out_size;
  const float* emb = (const float*)d_in[0];
  // d_in[1] (x) is shadowed in the reference; unused.
  const float* Wg  = (const float*)d_in[2];
  const float* W1  = (const float*)d_in[3];
  const float* b1  = (const float*)d_in[4];
  const float* W2  = (const float*)d_in[5];
  const float* b2  = (const float*)d_in[6];
  const float* W3  = (const float*)d_in[7];
  const float* b3  = (const float*)d_in[8];
  const float* Ws1 = (const float*)d_in[9];
  const float* bs1 = (const float*)d_in[10];
  const float* Ws2 = (const float*)d_in[11];
  const float* bs2 = (const float*)d_in[12];
  float* out = (float*)d_out;
  char* ws = (char*)d_ws;

  const size_t SZ_XB = (size_t)N_TOK*DIM*2;
  const size_t SZ_H1 = (size_t)N_TOK*KTOP*HID*2;
  const size_t SZ_HS = (size_t)N_TOK*SHID*2;
  const size_t SZ_T4 = (size_t)N_TOK*KTOP*4;
  const size_t SZ_WB = (size_t)NEXP*HID*DIM*2;
  const size_t SZ_SB = (size_t)SHID*DIM*2;
  const size_t SZ_YR = (size_t)N_TOK*KTOP*DIM*2;

  size_t off_xb = 0;
  size_t off_h1 = off_xb + SZ_XB;
  size_t off_hs = off_h1 + SZ_H1;
  size_t off_tw = off_hs + SZ_HS;
  size_t off_ti = off_tw + SZ_T4;
  size_t off_ro = off_ti + SZ_T4;
  size_t off_rw = off_ro + SZ_T4;
  size_t off_sl = off_rw + SZ_T4;
  size_t off_cnt = off_sl + SZ_T4;
  size_t off_off = off_cnt + 256;
  size_t off_cur = off_off + 256;
  size_t base_end = off_cur + 256;
  size_t off_w1b = base_end;
  size_t off_w3b = off_w1b + SZ_WB;
  size_t off_w2b = off_w3b + SZ_WB;
  size_t off_s1b = off_w2b + SZ_WB;
  size_t off_s2b = off_s1b + SZ_SB;
  size_t wbf_end = off_s2b + SZ_SB;

  bool wbf = ws_size >= wbf_end;                 // bf16 weight cache fits?
  size_t off_yr = wbf ? wbf_end : base_end;
  bool comb = ws_size >= off_yr + SZ_YR;         // deterministic combine path fits?

  unsigned short* Xb = (unsigned short*)(ws + off_xb);
  unsigned short* H1 = (unsigned short*)(ws + off_h1);
  unsigned short* Hs = (unsigned short*)(ws + off_hs);
  float* topw = (float*)(ws + off_tw);
  int*   topi = (int*)(ws + off_ti);
  int*   rowsL= (int*)(ws + off_ro);
  float* rwL  = (float*)(ws + off_rw);
  int*   slotL= (int*)(ws + off_sl);
  int*   cntP = (int*)(ws + off_cnt);
  int*   offP = (int*)(ws + off_off);
  int*   curP = (int*)(ws + off_cur);
  unsigned short* Yr = (unsigned short*)(ws + off_yr);

  hipMemsetAsync(ws + off_cnt, 0, 768, stream);
  k_cvt<<<2048, 256, 0, stream>>>(emb, Xb, (size_t)N_TOK*DIM/4);
  if (wbf){
    k_cvt<<<2048, 256, 0, stream>>>(W1,  (unsigned short*)(ws + off_w1b), (size_t)NEXP*HID*DIM/4);
    k_cvt<<<2048, 256, 0, stream>>>(W3,  (unsigned short*)(ws + off_w3b), (size_t)NEXP*HID*DIM/4);
    k_cvt<<<2048, 256, 0, stream>>>(W2,  (unsigned short*)(ws + off_w2b), (size_t)NEXP*HID*DIM/4);
    k_cvt<<<512,  256, 0, stream>>>(Ws1, (unsigned short*)(ws + off_s1b), (size_t)SHID*DIM/4);
    k_cvt<<<512,  256, 0, stream>>>(Ws2, (unsigned short*)(ws + off_s2b), (size_t)SHID*DIM/4);
  }
  k_gate<<<2048, 256, 0, stream>>>(emb, Wg, topw, topi, cntP);
  k_scan<<<1, 64, 0, stream>>>(cntP, offP, curP);
  k_place<<<32, 256, 0, stream>>>(topi, topw, curP, rowsL, rwL, slotL);

  dim3 g13g(704, 16);   // 11 col-tiles (H) x 64 row-tiles, rt fastest for B-panel L2 reuse
  if (wbf) k_g13<true ><<<g13g, 256, 0, stream>>>(Xb, ws+off_w1b, ws+off_w3b, b1, b3, rowsL, cntP, offP, H1);
  else     k_g13<false><<<g13g, 256, 0, stream>>>(Xb, W1, W3, b1, b3, rowsL, cntP, offP, H1);

  if (wbf) k_gemm<0,true ,32><<<1408, 256, 0, stream>>>(Xb, ws+off_s1b, bs1, nullptr, Hs, nullptr,nullptr,nullptr,nullptr);
  else     k_gemm<0,false,32><<<1408, 256, 0, stream>>>(Xb, Ws1, bs1, nullptr, Hs, nullptr,nullptr,nullptr,nullptr);

  if (wbf) k_gemm<1,true ,44><<<1024, 256, 0, stream>>>(Hs, ws+off_s2b, bs2, out, nullptr, nullptr,nullptr,nullptr,nullptr);
  else     k_gemm<1,false,44><<<1024, 256, 0, stream>>>(Hs, Ws2, bs2, out, nullptr, nullptr,nullptr,nullptr,nullptr);

  dim3 g2g(1024, 16);
  if (comb){
    if (wbf) k_gemm<3,true ,22><<<g2g, 256, 0, stream>>>(H1, ws+off_w2b, b2, nullptr, Yr, rowsL, rwL, cntP, offP);
    else     k_gemm<3,false,22><<<g2g, 256, 0, stream>>>(H1, W2, b2, nullptr, Yr, rowsL, rwL, cntP, offP);
    k_comb<<<N_TOK, 256, 0, stream>>>(Yr, slotL, out);
  } else {
    if (wbf) k_gemm<2,true ,22><<<g2g, 256, 0, stream>>>(H1, ws+off_w2b, b2, out, nullptr, rowsL, rwL, cntP, offP);
    else     k_gemm<2,false,22><<<g2g, 256, 0, stream>>>(H1, W2, b2, out, nullptr, rowsL, rwL, cntP, offP);
  }
}

// Round 3
// 2185.815 us; speedup vs baseline: 1.4498x; 1.4498x over previous
//
#include <hip/hip_runtime.h>
#include <stdint.h>

#define N_TOK 8192
#define DIM   2048
#define NEXP  16
#define HID   1408
#define SHID  2816
#define KTOP  4
#define TILEMAX 272   // worst-case routed row-tiles: sum ceil(cnt/128) <= 256+15

typedef __attribute__((ext_vector_type(8))) short bf16x8;
typedef __attribute__((ext_vector_type(4))) float f32x4;

#define MFMA16(a,b,c) __builtin_amdgcn_mfma_f32_16x16x32_bf16((a),(b),(c),0,0,0)

__device__ __forceinline__ unsigned short f2b(float f){
  unsigned u = __float_as_uint(f);
  return (unsigned short)((u + 0x7fffu + ((u >> 16) & 1u)) >> 16);  // RNE bf16
}
__device__ __forceinline__ unsigned pk2(float a, float b){
  return (unsigned)f2b(a) | ((unsigned)f2b(b) << 16);
}
__device__ __forceinline__ float bu2f(unsigned hs){ return __uint_as_float(hs << 16); }
__device__ __forceinline__ float siluf(float x){ return x / (1.f + expf(-x)); }
__device__ __forceinline__ f32x4 zero4(){ f32x4 z; z[0]=0.f; z[1]=0.f; z[2]=0.f; z[3]=0.f; return z; }

// async global->LDS, 16B per lane. LDS dest is wave-uniform base + lane*16 (linear).
__device__ __forceinline__ void gll16(const unsigned short* g, unsigned short* l){
  __builtin_amdgcn_global_load_lds(
      (const __attribute__((address_space(1))) void*)g,
      (__attribute__((address_space(3))) void*)l, 16, 0, 0);
}

// ---------------- fp32 -> bf16 convert (vectorized) ----------------
__global__ __launch_bounds__(256) void k_cvt(const float* __restrict__ s,
                                             unsigned short* __restrict__ d, size_t n4){
  size_t i = (size_t)blockIdx.x*256 + threadIdx.x;
  size_t st = (size_t)gridDim.x*256;
  for (; i < n4; i += st){
    float4 v = ((const float4*)s)[i];
    uint2 q; q.x = pk2(v.x, v.y); q.y = pk2(v.z, v.w);
    ((uint2*)d)[i] = q;
  }
}

// ---------------- gate: fp32 logits, softmax, top-4 (wave per token) ----------------
__global__ __launch_bounds__(256) void k_gate(const float* __restrict__ X, const float* __restrict__ Wg,
                                              float* __restrict__ topw, int* __restrict__ topi,
                                              int* __restrict__ cnt){
  int lane = threadIdx.x & 63;
  int t = blockIdx.x*4 + (threadIdx.x >> 6);
  const float* xr = X + (size_t)t*DIM;
  float xv[32];
#pragma unroll
  for (int i=0;i<32;i++) xv[i] = xr[i*64 + lane];
  float sc[NEXP];
#pragma unroll
  for (int e=0;e<NEXP;e++){
    const float* wr = Wg + e*DIM;
    float s = 0.f;
#pragma unroll
    for (int i=0;i<32;i++) s = fmaf(xv[i], wr[i*64 + lane], s);
#pragma unroll
    for (int d=1; d<64; d<<=1) s += __shfl_xor(s, d);
    sc[e] = s;
  }
  if (lane == 0){
    float m = sc[0];
#pragma unroll
    for (int e=1;e<NEXP;e++) m = fmaxf(m, sc[e]);
    float den = 0.f;
#pragma unroll
    for (int e=0;e<NEXP;e++){ sc[e] = expf(sc[e]-m); den += sc[e]; }
    float inv = 1.f/den;
#pragma unroll
    for (int e=0;e<NEXP;e++) sc[e] *= inv;
    for (int k=0;k<KTOP;k++){
      int bi = 0; float bv = sc[0];
#pragma unroll
      for (int e=1;e<NEXP;e++) if (sc[e] > bv){ bv = sc[e]; bi = e; }
      topw[t*KTOP+k] = bv;           // ROUTE_SCALE == 1
      topi[t*KTOP+k] = bi;
#pragma unroll
      for (int e=0;e<NEXP;e++) if (e == bi) sc[e] = -1.f;   // static-index kill
      atomicAdd(&cnt[bi], 1);
    }
  }
}

// scan + compact work-tile table: tab[i] = (expert<<16)|row_tile, -1 padded.
__global__ void k_scan(const int* __restrict__ cnt, int* __restrict__ off, int* __restrict__ cur,
                       int* __restrict__ tab){
  if (threadIdx.x == 0){
    int a = 0;
    for (int e=0;e<NEXP;e++){ off[e] = a; cur[e] = a; a += cnt[e]; }
    int n = 0;
    for (int e=0;e<NEXP;e++){
      int nt = (cnt[e] + 127) >> 7;
      for (int r=0;r<nt;r++) tab[n++] = (e << 16) | r;
    }
    for (; n < TILEMAX; ++n) tab[n] = -1;
  }
}

__global__ __launch_bounds__(256) void k_place(const int* __restrict__ topi, const float* __restrict__ topw,
                                               int* __restrict__ cur, int* __restrict__ rows,
                                               float* __restrict__ rw, int* __restrict__ slotL){
  int t = blockIdx.x*256 + threadIdx.x;
#pragma unroll
  for (int k=0;k<KTOP;k++){
    int e = topi[t*KTOP+k];
    int p = atomicAdd(&cur[e], 1);
    rows[p] = t;
    rw[p]   = topw[t*KTOP+k];
    slotL[t*KTOP+k] = p;
  }
}

// fp32-weight fallback staging (reg-staged, writes the same swizzled layout)
__device__ __forceinline__ void stage_Bf(unsigned short* lsB, const float* bF,
                                         int ldK, int bn0, int k0, int tid){
#pragma unroll
  for (int j=0;j<8;j++){
    int idx = j*256 + tid, r = idx >> 4, c4 = idx & 15;
    float4 v = *(const float4*)(bF + (size_t)(bn0 + r)*ldK + k0 + c4*4);
    uint2 q; q.x = pk2(v.x, v.y); q.y = pk2(v.z, v.w);
    *(uint2*)&lsB[r*64 + (((c4 >> 1) ^ (r & 7)) << 3) + ((c4 & 1) << 2)] = q;
  }
}

__device__ __forceinline__ void read_A(bf16x8 af[4], const unsigned short* lsA, int wm, int lane, int kc){
  int s = kc*4 + (lane >> 4);
#pragma unroll
  for (int mi=0;mi<4;mi++){
    int r = wm + mi*16 + (lane & 15);
    af[mi] = *(const bf16x8*)&lsA[r*64 + ((s ^ (r & 7)) << 3)];
  }
}

// ---------------- routed up+gate proj: H1 = silu(A@W1^T+b1)*(A@W3^T+b3), gathered rows ----------------
// 128x128x64 tile, 4 waves. Staging: global_load_lds w=16, linear LDS dest,
// source k-chunk pre-XOR'd (c = (l&7)^((l>>3)&7)) to match read-side swizzle.
// Grid: x = ct (11 col tiles of HID), y = compact tile slot (expert,row-tile).
template<bool WBF>
__global__ __launch_bounds__(256) void k_g13(const unsigned short* __restrict__ Xb,
    const void* __restrict__ W1p, const void* __restrict__ W3p,
    const float* __restrict__ b1, const float* __restrict__ b3,
    const int* __restrict__ rows, const int* __restrict__ cnt, const int* __restrict__ offs,
    const int* __restrict__ tab, unsigned short* __restrict__ H1)
{
  int ent = tab[blockIdx.y];
  if (ent < 0) return;
  int e = ent >> 16, rt = ent & 0xffff, ct = blockIdx.x;
  int cntE = cnt[e];
  int offE = offs[e];
  int hn0 = ct*128;
  int tid = threadIdx.x, lane = tid & 63, wid = tid >> 6;
  int wm = (wid >> 1)*64, wn = (wid & 1)*64;
  __shared__ alignas(16) unsigned short lsA[8192], lsB1[8192], lsB3[8192];

  int lr8 = lane >> 3;            // row within 8-row group
  int cx  = (lane & 7) ^ lr8;     // pre-swizzled source k-chunk (involution of read XOR)
  unsigned offA[4], offB[4];
#pragma unroll
  for (int j=0;j<4;j++){
    int r = wid*32 + j*8 + lr8;   // r&7 == lr8
    int lrow = rt*128 + r;
    int arow = rows[offE + (lrow < cntE ? lrow : cntE-1)];
    offA[j] = (unsigned)arow*DIM + (unsigned)cx*8;
    offB[j] = (unsigned)(hn0 + r)*DIM + (unsigned)cx*8;
  }
  const unsigned short* b1H = (const unsigned short*)W1p + (size_t)e*HID*DIM;
  const unsigned short* b3H = (const unsigned short*)W3p + (size_t)e*HID*DIM;
  const float* b1F = (const float*)W1p + (size_t)e*HID*DIM;
  const float* b3F = (const float*)W3p + (size_t)e*HID*DIM;
  unsigned short* lA  = &lsA[wid*2048];
  unsigned short* lB1 = &lsB1[wid*2048];
  unsigned short* lB3 = &lsB3[wid*2048];

  f32x4 acc1[4][4], acc3[4][4];
#pragma unroll
  for (int i=0;i<4;i++)
#pragma unroll
    for (int j=0;j<4;j++){ acc1[i][j] = zero4(); acc3[i][j] = zero4(); }

  for (int kt=0; kt<DIM/64; ++kt){
    int k0 = kt*64;
    __syncthreads();
#pragma unroll
    for (int j=0;j<4;j++){
      gll16(Xb + offA[j] + k0, lA + j*512);
      if constexpr (WBF){
        gll16(b1H + offB[j] + k0, lB1 + j*512);
        gll16(b3H + offB[j] + k0, lB3 + j*512);
      }
    }
    if constexpr (!WBF){
      stage_Bf(lsB1, b1F, DIM, hn0, k0, tid);
      stage_Bf(lsB3, b3F, DIM, hn0, k0, tid);
    }
    __syncthreads();   // compiler drains vmcnt/lgkmcnt here -> staged data visible
#pragma unroll
    for (int kc=0;kc<2;kc++){
      bf16x8 af[4]; read_A(af, lsA, wm, lane, kc);
      int sB = kc*4 + (lane >> 4);
#pragma unroll
      for (int nj=0;nj<4;nj++){
        int rb = wn + nj*16 + (lane & 15);
        int lof = rb*64 + ((sB ^ (rb & 7)) << 3);
        bf16x8 bf1 = *(const bf16x8*)&lsB1[lof];
        bf16x8 bf3 = *(const bf16x8*)&lsB3[lof];
#pragma unroll
        for (int mi=0;mi<4;mi++){
          acc1[mi][nj] = MFMA16(af[mi], bf1, acc1[mi][nj]);
          acc3[mi][nj] = MFMA16(af[mi], bf3, acc3[mi][nj]);
        }
      }
    }
  }
#pragma unroll
  for (int nj=0;nj<4;nj++){
    int h = hn0 + wn + nj*16 + (lane & 15);
    float b1v = b1[e*HID + h];
    float b3v = b3[e*HID + h];
#pragma unroll
    for (int mi=0;mi<4;mi++){
#pragma unroll
      for (int r=0;r<4;r++){
        int gr = rt*128 + wm + mi*16 + (lane >> 4)*4 + r;
        if (gr < cntE){
          float u = acc1[mi][nj][r] + b1v;
          float v = acc3[mi][nj][r] + b3v;
          H1[(size_t)(offE + gr)*HID + h] = f2b(siluf(u)*v);
        }
      }
    }
  }
}

// ---------------- generic single-B GEMM: MODE 0=gs1(silu->Hs) 1=gs2(store out) 2=g2 atomic 3=g2->Yrows ----------------
// MODE>=2: grid x = ct (16 col tiles of DIM), y = compact tile slot.
// MODE<2 : grid x = ct*64 + rt (dense, no early exit).
template<int MODE, bool WBF, int KSTEPS>
__global__ __launch_bounds__(256) void k_gemm(const unsigned short* __restrict__ Abase,
    const void* __restrict__ Bpv, const float* __restrict__ bias,
    float* __restrict__ outF, unsigned short* __restrict__ outH,
    const int* __restrict__ rows, const float* __restrict__ rw,
    const int* __restrict__ cnt, const int* __restrict__ offs,
    const int* __restrict__ tab)
{
  constexpr int KD = KSTEPS*64;
  int e = 0, ct, rt, cntE = 0, offE = 0;
  if constexpr (MODE >= 2){
    int ent = tab[blockIdx.y];
    if (ent < 0) return;
    e = ent >> 16; rt = ent & 0xffff; ct = blockIdx.x;
    cntE = cnt[e];
    offE = offs[e];
  } else {
    ct = blockIdx.x >> 6; rt = blockIdx.x & 63;
  }
  int bn0 = ct*128, t0 = rt*128;
  int tid = threadIdx.x, lane = tid & 63, wid = tid >> 6;
  int wm = (wid >> 1)*64, wn = (wid & 1)*64;
  __shared__ alignas(16) unsigned short lsA[8192], lsB[8192];

  int lr8 = lane >> 3;
  int cx  = (lane & 7) ^ lr8;
  unsigned offA[4], offB[4];
#pragma unroll
  for (int j=0;j<4;j++){
    int r = wid*32 + j*8 + lr8;
    int arow;
    if constexpr (MODE >= 2){
      int lrow = t0 + r;
      arow = offE + (lrow < cntE ? lrow : cntE-1);
    } else arow = t0 + r;
    offA[j] = (unsigned)arow*KD + (unsigned)cx*8;
    offB[j] = (unsigned)(bn0 + r)*KD + (unsigned)cx*8;
  }
  const unsigned short* bH = (const unsigned short*)Bpv + ((MODE >= 2) ? (size_t)e*2048*KD : (size_t)0);
  const float*          bF = (const float*)Bpv          + ((MODE >= 2) ? (size_t)e*2048*KD : (size_t)0);
  const float* biasp = bias + ((MODE >= 2) ? e*DIM : 0);
  unsigned short* lA = &lsA[wid*2048];
  unsigned short* lB = &lsB[wid*2048];

  f32x4 acc[4][4];
#pragma unroll
  for (int i=0;i<4;i++)
#pragma unroll
    for (int j=0;j<4;j++) acc[i][j] = zero4();

  for (int kt=0; kt<KSTEPS; ++kt){
    int k0 = kt*64;
    __syncthreads();
#pragma unroll
    for (int j=0;j<4;j++){
      gll16(Abase + offA[j] + k0, lA + j*512);
      if constexpr (WBF) gll16(bH + offB[j] + k0, lB + j*512);
    }
    if constexpr (!WBF) stage_Bf(lsB, bF, KD, bn0, k0, tid);
    __syncthreads();
#pragma unroll
    for (int kc=0;kc<2;kc++){
      bf16x8 af[4]; read_A(af, lsA, wm, lane, kc);
      int sB = kc*4 + (lane >> 4);
#pragma unroll
      for (int nj=0;nj<4;nj++){
        int rb = wn + nj*16 + (lane & 15);
        bf16x8 bfr = *(const bf16x8*)&lsB[rb*64 + ((sB ^ (rb & 7)) << 3)];
#pragma unroll
        for (int mi=0;mi<4;mi++)
          acc[mi][nj] = MFMA16(af[mi], bfr, acc[mi][nj]);
      }
    }
  }
#pragma unroll
  for (int nj=0;nj<4;nj++){
    int col = bn0 + wn + nj*16 + (lane & 15);
    float bv = biasp[col];
#pragma unroll
    for (int mi=0;mi<4;mi++){
#pragma unroll
      for (int r=0;r<4;r++){
        int lr = wm + mi*16 + (lane >> 4)*4 + r;
        float v = acc[mi][nj][r] + bv;
        if constexpr (MODE == 0){
          outH[(size_t)(t0 + lr)*SHID + col] = f2b(siluf(v));
        } else if constexpr (MODE == 1){
          outF[(size_t)(t0 + lr)*DIM + col] = v;
        } else {
          int gr = t0 + lr;
          if (gr < cntE){
            int slot = offE + gr;
            float wv = rw[slot] * v;
            if constexpr (MODE == 2){
              atomicAdd(outF + (size_t)rows[slot]*DIM + col, wv);
            } else {
              outH[(size_t)slot*DIM + col] = f2b(wv);
            }
          }
        }
      }
    }
  }
}

// ---------------- deterministic combine: out += sum_k Yrows[slot(t,k)] ----------------
__global__ __launch_bounds__(256) void k_comb(const unsigned short* __restrict__ Yr,
                                              const int* __restrict__ slotL, float* __restrict__ out){
  int i = blockIdx.x*256 + threadIdx.x;
  int t = i >> 8, c = i & 255;
  size_t ob = (size_t)t*DIM + (size_t)c*8;
  float4 a = *(float4*)(out + ob);
  float4 b = *(float4*)(out + ob + 4);
  int sl[4];
#pragma unroll
  for (int k=0;k<KTOP;k++) sl[k] = slotL[t*KTOP + k];
#pragma unroll
  for (int k=0;k<KTOP;k++){
    uint4 v = *(const uint4*)(Yr + (size_t)sl[k]*DIM + (size_t)c*8);
    a.x += bu2f(v.x & 0xffffu); a.y += bu2f(v.x >> 16);
    a.z += bu2f(v.y & 0xffffu); a.w += bu2f(v.y >> 16);
    b.x += bu2f(v.z & 0xffffu); b.y += bu2f(v.z >> 16);
    b.z += bu2f(v.w & 0xffffu); b.w += bu2f(v.w >> 16);
  }
  *(float4*)(out + ob) = a;
  *(float4*)(out + ob + 4) = b;
}

// ---------------- host ----------------
extern "C" void kernel_launch(void* const* d_in, const int* in_sizes, int n_in,
                              void* d_out, int out_size, void* d_ws, size_t ws_size,
                              hipStream_t stream)
{
  (void)in_sizes; (void)n_in; (void)out_size;
  const float* emb = (const float*)d_in[0];
  // d_in[1] (x) is shadowed in the reference; unused.
  const float* Wg  = (const float*)d_in[2];
  const float* W1  = (const float*)d_in[3];
  const float* b1  = (const float*)d_in[4];
  const float* W2  = (const float*)d_in[5];
  const float* b2  = (const float*)d_in[6];
  const float* W3  = (const float*)d_in[7];
  const float* b3  = (const float*)d_in[8];
  const float* Ws1 = (const float*)d_in[9];
  const float* bs1 = (const float*)d_in[10];
  const float* Ws2 = (const float*)d_in[11];
  const float* bs2 = (const float*)d_in[12];
  float* out = (float*)d_out;
  char* ws = (char*)d_ws;

  const size_t SZ_XB = (size_t)N_TOK*DIM*2;
  const size_t SZ_H1 = (size_t)N_TOK*KTOP*HID*2;
  const size_t SZ_HS = (size_t)N_TOK*SHID*2;
  const size_t SZ_T4 = (size_t)N_TOK*KTOP*4;
  const size_t SZ_WB = (size_t)NEXP*HID*DIM*2;
  const size_t SZ_SB = (size_t)SHID*DIM*2;
  const size_t SZ_YR = (size_t)N_TOK*KTOP*DIM*2;

  size_t off_xb = 0;
  size_t off_h1 = off_xb + SZ_XB;
  size_t off_hs = off_h1 + SZ_H1;
  size_t off_tw = off_hs + SZ_HS;
  size_t off_ti = off_tw + SZ_T4;
  size_t off_ro = off_ti + SZ_T4;
  size_t off_rw = off_ro + SZ_T4;
  size_t off_sl = off_rw + SZ_T4;
  size_t off_cnt = off_sl + SZ_T4;
  size_t off_off = off_cnt + 256;
  size_t off_cur = off_off + 256;
  size_t off_tab = off_cur + 256;
  size_t base_end = off_tab + TILEMAX*4 + 64;
  size_t off_w1b = base_end;
  size_t off_w3b = off_w1b + SZ_WB;
  size_t off_w2b = off_w3b + SZ_WB;
  size_t off_s1b = off_w2b + SZ_WB;
  size_t off_s2b = off_s1b + SZ_SB;
  size_t wbf_end = off_s2b + SZ_SB;

  bool wbf = ws_size >= wbf_end;                 // bf16 weight cache fits?
  size_t off_yr = wbf ? wbf_end : base_end;
  bool comb = ws_size >= off_yr + SZ_YR;         // deterministic combine path fits?

  unsigned short* Xb = (unsigned short*)(ws + off_xb);
  unsigned short* H1 = (unsigned short*)(ws + off_h1);
  unsigned short* Hs = (unsigned short*)(ws + off_hs);
  float* topw = (float*)(ws + off_tw);
  int*   topi = (int*)(ws + off_ti);
  int*   rowsL= (int*)(ws + off_ro);
  float* rwL  = (float*)(ws + off_rw);
  int*   slotL= (int*)(ws + off_sl);
  int*   cntP = (int*)(ws + off_cnt);
  int*   offP = (int*)(ws + off_off);
  int*   curP = (int*)(ws + off_cur);
  int*   tabP = (int*)(ws + off_tab);
  unsigned short* Yr = (unsigned short*)(ws + off_yr);

  hipMemsetAsync(ws + off_cnt, 0, 768, stream);
  k_cvt<<<2048, 256, 0, stream>>>(emb, Xb, (size_t)N_TOK*DIM/4);
  if (wbf){
    k_cvt<<<2048, 256, 0, stream>>>(W1,  (unsigned short*)(ws + off_w1b), (size_t)NEXP*HID*DIM/4);
    k_cvt<<<2048, 256, 0, stream>>>(W3,  (unsigned short*)(ws + off_w3b), (size_t)NEXP*HID*DIM/4);
    k_cvt<<<2048, 256, 0, stream>>>(W2,  (unsigned short*)(ws + off_w2b), (size_t)NEXP*HID*DIM/4);
    k_cvt<<<512,  256, 0, stream>>>(Ws1, (unsigned short*)(ws + off_s1b), (size_t)SHID*DIM/4);
    k_cvt<<<512,  256, 0, stream>>>(Ws2, (unsigned short*)(ws + off_s2b), (size_t)SHID*DIM/4);
  }
  k_gate<<<2048, 256, 0, stream>>>(emb, Wg, topw, topi, cntP);
  k_scan<<<1, 64, 0, stream>>>(cntP, offP, curP, tabP);
  k_place<<<32, 256, 0, stream>>>(topi, topw, curP, rowsL, rwL, slotL);

  dim3 g13g(11, TILEMAX);   // x = ct (HID col tiles), y = compact (expert,row-tile) slots
  if (wbf) k_g13<true ><<<g13g, 256, 0, stream>>>(Xb, ws+off_w1b, ws+off_w3b, b1, b3, rowsL, cntP, offP, tabP, H1);
  else     k_g13<false><<<g13g, 256, 0, stream>>>(Xb, W1, W3, b1, b3, rowsL, cntP, offP, tabP, H1);

  if (wbf) k_gemm<0,true ,32><<<1408, 256, 0, stream>>>(Xb, ws+off_s1b, bs1, nullptr, Hs, nullptr,nullptr,nullptr,nullptr,nullptr);
  else     k_gemm<0,false,32><<<1408, 256, 0, stream>>>(Xb, Ws1, bs1, nullptr, Hs, nullptr,nullptr,nullptr,nullptr,nullptr);

  if (wbf) k_gemm<1,true ,44><<<1024, 256, 0, stream>>>(Hs, ws+off_s2b, bs2, out, nullptr, nullptr,nullptr,nullptr,nullptr,nullptr);
  else     k_gemm<1,false,44><<<1024, 256, 0, stream>>>(Hs, Ws2, bs2, out, nullptr, nullptr,nullptr,nullptr,nullptr,nullptr);

  dim3 g2g(16, TILEMAX);    // x = ct (DIM col tiles), y = compact tile slots
  if (comb){
    if (wbf) k_gemm<3,true ,22><<<g2g, 256, 0, stream>>>(H1, ws+off_w2b, b2, nullptr, Yr, rowsL, rwL, cntP, offP, tabP);
    else     k_gemm<3,false,22><<<g2g, 256, 0, stream>>>(H1, W2, b2, nullptr, Yr, rowsL, rwL, cntP, offP, tabP);
    k_comb<<<N_TOK, 256, 0, stream>>>(Yr, slotL, out);
  } else {
    if (wbf) k_gemm<2,true ,22><<<g2g, 256, 0, stream>>>(H1, ws+off_w2b, b2, out, nullptr, rowsL, rwL, cntP, offP, tabP);
    else     k_gemm<2,false,22><<<g2g, 256, 0, stream>>>(H1, W2, b2, out, nullptr, rowsL, rwL, cntP, offP, tabP);
  }
}

// Round 4
// 1768.126 us; speedup vs baseline: 1.7923x; 1.2362x over previous
//
#include <hip/hip_runtime.h>
#include <stdint.h>

#define N_TOK 8192
#define DIM   2048
#define NEXP  16
#define HID   1408
#define SHID  2816
#define KTOP  4
#define TILEMAX 272   // worst-case routed row-tiles: sum ceil(cnt/128) <= 256+15; 272 = 8*34

typedef __attribute__((ext_vector_type(8))) short bf16x8;
typedef __attribute__((ext_vector_type(4))) float f32x4;

#define MFMA16(a,b,c) __builtin_amdgcn_mfma_f32_16x16x32_bf16((a),(b),(c),0,0,0)

__device__ __forceinline__ unsigned short f2b(float f){
  unsigned u = __float_as_uint(f);
  return (unsigned short)((u + 0x7fffu + ((u >> 16) & 1u)) >> 16);  // RNE bf16
}
__device__ __forceinline__ unsigned pk2(float a, float b){
  return (unsigned)f2b(a) | ((unsigned)f2b(b) << 16);
}
__device__ __forceinline__ float bu2f(unsigned hs){ return __uint_as_float(hs << 16); }
__device__ __forceinline__ float siluf(float x){ return x / (1.f + expf(-x)); }
__device__ __forceinline__ f32x4 zero4(){ f32x4 z; z[0]=0.f; z[1]=0.f; z[2]=0.f; z[3]=0.f; return z; }

// async global->LDS, 16B per lane. LDS dest is wave-uniform base + lane*16 (linear).
__device__ __forceinline__ void gll16(const unsigned short* g, unsigned short* l){
  __builtin_amdgcn_global_load_lds(
      (const __attribute__((address_space(1))) void*)g,
      (__attribute__((address_space(3))) void*)l, 16, 0, 0);
}

// ---------------- fp32 -> bf16 convert (vectorized) ----------------
__global__ __launch_bounds__(256) void k_cvt(const float* __restrict__ s,
                                             unsigned short* __restrict__ d, size_t n4){
  size_t i = (size_t)blockIdx.x*256 + threadIdx.x;
  size_t st = (size_t)gridDim.x*256;
  for (; i < n4; i += st){
    float4 v = ((const float4*)s)[i];
    uint2 q; q.x = pk2(v.x, v.y); q.y = pk2(v.z, v.w);
    ((uint2*)d)[i] = q;
  }
}

// ---------------- gate: fp32 logits, softmax, top-4 (wave per token) ----------------
__global__ __launch_bounds__(256) void k_gate(const float* __restrict__ X, const float* __restrict__ Wg,
                                              float* __restrict__ topw, int* __restrict__ topi,
                                              int* __restrict__ cnt){
  int lane = threadIdx.x & 63;
  int t = blockIdx.x*4 + (threadIdx.x >> 6);
  const float* xr = X + (size_t)t*DIM;
  float xv[32];
#pragma unroll
  for (int i=0;i<32;i++) xv[i] = xr[i*64 + lane];
  float sc[NEXP];
#pragma unroll
  for (int e=0;e<NEXP;e++){
    const float* wr = Wg + e*DIM;
    float s = 0.f;
#pragma unroll
    for (int i=0;i<32;i++) s = fmaf(xv[i], wr[i*64 + lane], s);
#pragma unroll
    for (int d=1; d<64; d<<=1) s += __shfl_xor(s, d);
    sc[e] = s;
  }
  if (lane == 0){
    float m = sc[0];
#pragma unroll
    for (int e=1;e<NEXP;e++) m = fmaxf(m, sc[e]);
    float den = 0.f;
#pragma unroll
    for (int e=0;e<NEXP;e++){ sc[e] = expf(sc[e]-m); den += sc[e]; }
    float inv = 1.f/den;
#pragma unroll
    for (int e=0;e<NEXP;e++) sc[e] *= inv;
    for (int k=0;k<KTOP;k++){
      int bi = 0; float bv = sc[0];
#pragma unroll
      for (int e=1;e<NEXP;e++) if (sc[e] > bv){ bv = sc[e]; bi = e; }
      topw[t*KTOP+k] = bv;           // ROUTE_SCALE == 1
      topi[t*KTOP+k] = bi;
#pragma unroll
      for (int e=0;e<NEXP;e++) if (e == bi) sc[e] = -1.f;   // static-index kill
      atomicAdd(&cnt[bi], 1);
    }
  }
}

// scan + compact work-tile table: tab[i] = (expert<<16)|row_tile, -1 padded.
__global__ void k_scan(const int* __restrict__ cnt, int* __restrict__ off, int* __restrict__ cur,
                       int* __restrict__ tab){
  if (threadIdx.x == 0){
    int a = 0;
    for (int e=0;e<NEXP;e++){ off[e] = a; cur[e] = a; a += cnt[e]; }
    int n = 0;
    for (int e=0;e<NEXP;e++){
      int nt = (cnt[e] + 127) >> 7;
      for (int r=0;r<nt;r++) tab[n++] = (e << 16) | r;
    }
    for (; n < TILEMAX; ++n) tab[n] = -1;
  }
}

__global__ __launch_bounds__(256) void k_place(const int* __restrict__ topi, const float* __restrict__ topw,
                                               int* __restrict__ cur, int* __restrict__ rows,
                                               float* __restrict__ rw, int* __restrict__ slotL){
  int t = blockIdx.x*256 + threadIdx.x;
#pragma unroll
  for (int k=0;k<KTOP;k++){
    int e = topi[t*KTOP+k];
    int p = atomicAdd(&cur[e], 1);
    rows[p] = t;
    rw[p]   = topw[t*KTOP+k];
    slotL[t*KTOP+k] = p;
  }
}

// fp32-weight fallback staging (reg-staged, writes the same swizzled layout)
__device__ __forceinline__ void stage_Bf(unsigned short* lsB, const float* bF,
                                         int ldK, int bn0, int k0, int tid){
#pragma unroll
  for (int j=0;j<8;j++){
    int idx = j*256 + tid, r = idx >> 4, c4 = idx & 15;
    float4 v = *(const float4*)(bF + (size_t)(bn0 + r)*ldK + k0 + c4*4);
    uint2 q; q.x = pk2(v.x, v.y); q.y = pk2(v.z, v.w);
    *(uint2*)&lsB[r*64 + (((c4 >> 1) ^ (r & 7)) << 3) + ((c4 & 1) << 2)] = q;
  }
}

__device__ __forceinline__ void read_A(bf16x8 af[4], const unsigned short* lsA, int wm, int lane, int kc){
  int s = kc*4 + (lane >> 4);
#pragma unroll
  for (int mi=0;mi<4;mi++){
    int r = wm + mi*16 + (lane & 15);
    af[mi] = *(const bf16x8*)&lsA[r*64 + ((s ^ (r & 7)) << 3)];
  }
}

// ---------------- routed up+gate proj: H1 = silu(A@W1^T+b1)*(A@W3^T+b3), gathered rows ----------------
// 128x128x64 tile, 4 waves. global_load_lds w=16, linear LDS dest, source pre-XOR'd.
// Flat grid 2992 = 8 XCD * (11 ct * 34 slots): each XCD owns 34 contiguous (e,rt)
// slots -> B1/B3 working set ~2.2MB stays L2-hot; A tiles stream from L3.
// __launch_bounds__(256,2): combined arch+acc regs <= 256 -> 2 blocks/CU resident.
template<bool WBF>
__global__ __launch_bounds__(256,2) void k_g13(const unsigned short* __restrict__ Xb,
    const void* __restrict__ W1p, const void* __restrict__ W3p,
    const float* __restrict__ b1, const float* __restrict__ b3,
    const int* __restrict__ rows, const int* __restrict__ cnt, const int* __restrict__ offs,
    const int* __restrict__ tab, unsigned short* __restrict__ H1)
{
  int bid = blockIdx.x;
  int l = bid >> 3;
  int ct = l / 34;
  int slot = (bid & 7)*34 + (l - ct*34);
  int ent = tab[slot];
  if (ent < 0) return;
  int e = ent >> 16, rt = ent & 0xffff;
  int cntE = cnt[e];
  int offE = offs[e];
  int hn0 = ct*128;
  int tid = threadIdx.x, lane = tid & 63, wid = tid >> 6;
  int wm = (wid >> 1)*64, wn = (wid & 1)*64;
  __shared__ alignas(16) unsigned short lsA[8192], lsB1[8192], lsB3[8192];

  int lr8 = lane >> 3;            // row within 8-row group
  int cx  = (lane & 7) ^ lr8;     // pre-swizzled source k-chunk (involution of read XOR)
  unsigned offA[4];
#pragma unroll
  for (int j=0;j<4;j++){
    int lrow = rt*128 + wid*32 + j*8 + lr8;   // (row & 7) == lr8
    int arow = rows[offE + (lrow < cntE ? lrow : cntE-1)];
    offA[j] = (unsigned)arow*DIM + (unsigned)cx*8;
  }
  unsigned offB0 = (unsigned)(hn0 + wid*32 + lr8)*DIM + (unsigned)cx*8;  // + j*8*DIM
  const unsigned short* b1H = (const unsigned short*)W1p + (size_t)e*HID*DIM;
  const unsigned short* b3H = (const unsigned short*)W3p + (size_t)e*HID*DIM;
  const float* b1F = (const float*)W1p + (size_t)e*HID*DIM;
  const float* b3F = (const float*)W3p + (size_t)e*HID*DIM;
  unsigned short* lA  = &lsA[wid*2048];
  unsigned short* lB1 = &lsB1[wid*2048];
  unsigned short* lB3 = &lsB3[wid*2048];

  f32x4 acc1[4][4], acc3[4][4];
#pragma unroll
  for (int i=0;i<4;i++)
#pragma unroll
    for (int j=0;j<4;j++){ acc1[i][j] = zero4(); acc3[i][j] = zero4(); }

  for (int kt=0; kt<DIM/64; ++kt){
    int k0 = kt*64;
    __syncthreads();
#pragma unroll
    for (int j=0;j<4;j++){
      gll16(Xb + offA[j] + k0, lA + j*512);
      if constexpr (WBF){
        gll16(b1H + offB0 + j*(8*DIM) + k0, lB1 + j*512);
        gll16(b3H + offB0 + j*(8*DIM) + k0, lB3 + j*512);
      }
    }
    if constexpr (!WBF){
      stage_Bf(lsB1, b1F, DIM, hn0, k0, tid);
      stage_Bf(lsB3, b3F, DIM, hn0, k0, tid);
    }
    __syncthreads();   // compiler drains vmcnt/lgkmcnt here -> staged data visible
#pragma unroll
    for (int kc=0;kc<2;kc++){
      bf16x8 af[4]; read_A(af, lsA, wm, lane, kc);
      int sB = kc*4 + (lane >> 4);
#pragma unroll
      for (int nj=0;nj<4;nj++){
        int rb = wn + nj*16 + (lane & 15);
        int lof = rb*64 + ((sB ^ (rb & 7)) << 3);
        bf16x8 bf1 = *(const bf16x8*)&lsB1[lof];
        bf16x8 bf3 = *(const bf16x8*)&lsB3[lof];
#pragma unroll
        for (int mi=0;mi<4;mi++){
          acc1[mi][nj] = MFMA16(af[mi], bf1, acc1[mi][nj]);
          acc3[mi][nj] = MFMA16(af[mi], bf3, acc3[mi][nj]);
        }
      }
    }
  }
#pragma unroll
  for (int nj=0;nj<4;nj++){
    int h = hn0 + wn + nj*16 + (lane & 15);
    float b1v = b1[e*HID + h];
    float b3v = b3[e*HID + h];
#pragma unroll
    for (int mi=0;mi<4;mi++){
#pragma unroll
      for (int r=0;r<4;r++){
        int gr = rt*128 + wm + mi*16 + (lane >> 4)*4 + r;
        if (gr < cntE){
          float u = acc1[mi][nj][r] + b1v;
          float v = acc3[mi][nj][r] + b3v;
          H1[(size_t)(offE + gr)*HID + h] = f2b(siluf(u)*v);
        }
      }
    }
  }
}

// ---------------- generic single-B GEMM: MODE 0=gs1(silu->Hs) 1=gs2(store out) 2=g2 atomic 3=g2->Yrows ----------------
// MODE>=2: flat grid 4352 = 8 XCD * (16 ct * 34 slots), XCD-chunked like k_g13.
// MODE<2 : flat grid (22|16)*64, remapped rt=(bid&7)*8+(l&7), ct=l>>3 (B panel L2-hot per XCD).
template<int MODE, bool WBF, int KSTEPS>
__global__ __launch_bounds__(256,2) void k_gemm(const unsigned short* __restrict__ Abase,
    const void* __restrict__ Bpv, const float* __restrict__ bias,
    float* __restrict__ outF, unsigned short* __restrict__ outH,
    const int* __restrict__ rows, const float* __restrict__ rw,
    const int* __restrict__ cnt, const int* __restrict__ offs,
    const int* __restrict__ tab)
{
  constexpr int KD = KSTEPS*64;
  int e = 0, ct, rt, cntE = 0, offE = 0;
  int bid = blockIdx.x;
  int l = bid >> 3;
  if constexpr (MODE >= 2){
    ct = l / 34;
    int slot = (bid & 7)*34 + (l - ct*34);
    int ent = tab[slot];
    if (ent < 0) return;
    e = ent >> 16; rt = ent & 0xffff;
    cntE = cnt[e];
    offE = offs[e];
  } else {
    rt = (bid & 7)*8 + (l & 7);
    ct = l >> 3;
  }
  int bn0 = ct*128, t0 = rt*128;
  int tid = threadIdx.x, lane = tid & 63, wid = tid >> 6;
  int wm = (wid >> 1)*64, wn = (wid & 1)*64;
  __shared__ alignas(16) unsigned short lsA[8192], lsB[8192];

  int lr8 = lane >> 3;
  int cx  = (lane & 7) ^ lr8;
  unsigned offA0 = 0;
  unsigned offA[4];
  if constexpr (MODE >= 2){
#pragma unroll
    for (int j=0;j<4;j++){
      int lrow = t0 + wid*32 + j*8 + lr8;
      int arow = offE + (lrow < cntE ? lrow : cntE-1);
      offA[j] = (unsigned)arow*KD + (unsigned)cx*8;
    }
  } else {
    offA0 = (unsigned)(t0 + wid*32 + lr8)*KD + (unsigned)cx*8;  // + j*8*KD
  }
  unsigned offB0 = (unsigned)(bn0 + wid*32 + lr8)*KD + (unsigned)cx*8;   // + j*8*KD
  const unsigned short* bH = (const unsigned short*)Bpv + ((MODE >= 2) ? (size_t)e*2048*KD : (size_t)0);
  const float*          bF = (const float*)Bpv          + ((MODE >= 2) ? (size_t)e*2048*KD : (size_t)0);
  const float* biasp = bias + ((MODE >= 2) ? e*DIM : 0);
  unsigned short* lA = &lsA[wid*2048];
  unsigned short* lB = &lsB[wid*2048];

  f32x4 acc[4][4];
#pragma unroll
  for (int i=0;i<4;i++)
#pragma unroll
    for (int j=0;j<4;j++) acc[i][j] = zero4();

  for (int kt=0; kt<KSTEPS; ++kt){
    int k0 = kt*64;
    __syncthreads();
#pragma unroll
    for (int j=0;j<4;j++){
      if constexpr (MODE >= 2) gll16(Abase + offA[j] + k0, lA + j*512);
      else                     gll16(Abase + offA0 + j*(8*KD) + k0, lA + j*512);
      if constexpr (WBF)       gll16(bH + offB0 + j*(8*KD) + k0, lB + j*512);
    }
    if constexpr (!WBF) stage_Bf(lsB, bF, KD, bn0, k0, tid);
    __syncthreads();
#pragma unroll
    for (int kc=0;kc<2;kc++){
      bf16x8 af[4]; read_A(af, lsA, wm, lane, kc);
      int sB = kc*4 + (lane >> 4);
#pragma unroll
      for (int nj=0;nj<4;nj++){
        int rb = wn + nj*16 + (lane & 15);
        bf16x8 bfr = *(const bf16x8*)&lsB[rb*64 + ((sB ^ (rb & 7)) << 3)];
#pragma unroll
        for (int mi=0;mi<4;mi++)
          acc[mi][nj] = MFMA16(af[mi], bfr, acc[mi][nj]);
      }
    }
  }
#pragma unroll
  for (int nj=0;nj<4;nj++){
    int col = bn0 + wn + nj*16 + (lane & 15);
    float bv = biasp[col];
#pragma unroll
    for (int mi=0;mi<4;mi++){
#pragma unroll
      for (int r=0;r<4;r++){
        int lr = wm + mi*16 + (lane >> 4)*4 + r;
        float v = acc[mi][nj][r] + bv;
        if constexpr (MODE == 0){
          outH[(size_t)(t0 + lr)*SHID + col] = f2b(siluf(v));
        } else if constexpr (MODE == 1){
          outF[(size_t)(t0 + lr)*DIM + col] = v;
        } else {
          int gr = t0 + lr;
          if (gr < cntE){
            int slot = offE + gr;
            float wv = rw[slot] * v;
            if constexpr (MODE == 2){
              atomicAdd(outF + (size_t)rows[slot]*DIM + col, wv);
            } else {
              outH[(size_t)slot*DIM + col] = f2b(wv);
            }
          }
        }
      }
    }
  }
}

// ---------------- deterministic combine: out += sum_k Yrows[slot(t,k)] ----------------
__global__ __launch_bounds__(256) void k_comb(const unsigned short* __restrict__ Yr,
                                              const int* __restrict__ slotL, float* __restrict__ out){
  int i = blockIdx.x*256 + threadIdx.x;
  int t = i >> 8, c = i & 255;
  size_t ob = (size_t)t*DIM + (size_t)c*8;
  float4 a = *(float4*)(out + ob);
  float4 b = *(float4*)(out + ob + 4);
  int sl[4];
#pragma unroll
  for (int k=0;k<KTOP;k++) sl[k] = slotL[t*KTOP + k];
#pragma unroll
  for (int k=0;k<KTOP;k++){
    uint4 v = *(const uint4*)(Yr + (size_t)sl[k]*DIM + (size_t)c*8);
    a.x += bu2f(v.x & 0xffffu); a.y += bu2f(v.x >> 16);
    a.z += bu2f(v.y & 0xffffu); a.w += bu2f(v.y >> 16);
    b.x += bu2f(v.z & 0xffffu); b.y += bu2f(v.z >> 16);
    b.z += bu2f(v.w & 0xffffu); b.w += bu2f(v.w >> 16);
  }
  *(float4*)(out + ob) = a;
  *(float4*)(out + ob + 4) = b;
}

// ---------------- host ----------------
extern "C" void kernel_launch(void* const* d_in, const int* in_sizes, int n_in,
                              void* d_out, int out_size, void* d_ws, size_t ws_size,
                              hipStream_t stream)
{
  (void)in_sizes; (void)n_in; (void)out_size;
  const float* emb = (const float*)d_in[0];
  // d_in[1] (x) is shadowed in the reference; unused.
  const float* Wg  = (const float*)d_in[2];
  const float* W1  = (const float*)d_in[3];
  const float* b1  = (const float*)d_in[4];
  const float* W2  = (const float*)d_in[5];
  const float* b2  = (const float*)d_in[6];
  const float* W3  = (const float*)d_in[7];
  const float* b3  = (const float*)d_in[8];
  const float* Ws1 = (const float*)d_in[9];
  const float* bs1 = (const float*)d_in[10];
  const float* Ws2 = (const float*)d_in[11];
  const float* bs2 = (const float*)d_in[12];
  float* out = (float*)d_out;
  char* ws = (char*)d_ws;

  const size_t SZ_XB = (size_t)N_TOK*DIM*2;
  const size_t SZ_H1 = (size_t)N_TOK*KTOP*HID*2;
  const size_t SZ_HS = (size_t)N_TOK*SHID*2;
  const size_t SZ_T4 = (size_t)N_TOK*KTOP*4;
  const size_t SZ_WB = (size_t)NEXP*HID*DIM*2;
  const size_t SZ_SB = (size_t)SHID*DIM*2;
  const size_t SZ_YR = (size_t)N_TOK*KTOP*DIM*2;

  size_t off_xb = 0;
  size_t off_h1 = off_xb + SZ_XB;
  size_t off_hs = off_h1 + SZ_H1;
  size_t off_tw = off_hs + SZ_HS;
  size_t off_ti = off_tw + SZ_T4;
  size_t off_ro = off_ti + SZ_T4;
  size_t off_rw = off_ro + SZ_T4;
  size_t off_sl = off_rw + SZ_T4;
  size_t off_cnt = off_sl + SZ_T4;
  size_t off_off = off_cnt + 256;
  size_t off_cur = off_off + 256;
  size_t off_tab = off_cur + 256;
  size_t base_end = off_tab + TILEMAX*4 + 64;
  size_t off_w1b = base_end;
  size_t off_w3b = off_w1b + SZ_WB;
  size_t off_w2b = off_w3b + SZ_WB;
  size_t off_s1b = off_w2b + SZ_WB;
  size_t off_s2b = off_s1b + SZ_SB;
  size_t wbf_end = off_s2b + SZ_SB;

  bool wbf = ws_size >= wbf_end;                 // bf16 weight cache fits?
  size_t off_yr = wbf ? wbf_end : base_end;
  bool comb = ws_size >= off_yr + SZ_YR;         // deterministic combine path fits?

  unsigned short* Xb = (unsigned short*)(ws + off_xb);
  unsigned short* H1 = (unsigned short*)(ws + off_h1);
  unsigned short* Hs = (unsigned short*)(ws + off_hs);
  float* topw = (float*)(ws + off_tw);
  int*   topi = (int*)(ws + off_ti);
  int*   rowsL= (int*)(ws + off_ro);
  float* rwL  = (float*)(ws + off_rw);
  int*   slotL= (int*)(ws + off_sl);
  int*   cntP = (int*)(ws + off_cnt);
  int*   offP = (int*)(ws + off_off);
  int*   curP = (int*)(ws + off_cur);
  int*   tabP = (int*)(ws + off_tab);
  unsigned short* Yr = (unsigned short*)(ws + off_yr);

  hipMemsetAsync(ws + off_cnt, 0, 768, stream);
  k_cvt<<<2048, 256, 0, stream>>>(emb, Xb, (size_t)N_TOK*DIM/4);
  if (wbf){
    k_cvt<<<2048, 256, 0, stream>>>(W1,  (unsigned short*)(ws + off_w1b), (size_t)NEXP*HID*DIM/4);
    k_cvt<<<2048, 256, 0, stream>>>(W3,  (unsigned short*)(ws + off_w3b), (size_t)NEXP*HID*DIM/4);
    k_cvt<<<2048, 256, 0, stream>>>(W2,  (unsigned short*)(ws + off_w2b), (size_t)NEXP*HID*DIM/4);
    k_cvt<<<512,  256, 0, stream>>>(Ws1, (unsigned short*)(ws + off_s1b), (size_t)SHID*DIM/4);
    k_cvt<<<512,  256, 0, stream>>>(Ws2, (unsigned short*)(ws + off_s2b), (size_t)SHID*DIM/4);
  }
  k_gate<<<2048, 256, 0, stream>>>(emb, Wg, topw, topi, cntP);
  k_scan<<<1, 64, 0, stream>>>(cntP, offP, curP, tabP);
  k_place<<<32, 256, 0, stream>>>(topi, topw, curP, rowsL, rwL, slotL);

  // flat 2992 = 8 XCD * 11 ct * 34 slots
  if (wbf) k_g13<true ><<<2992, 256, 0, stream>>>(Xb, ws+off_w1b, ws+off_w3b, b1, b3, rowsL, cntP, offP, tabP, H1);
  else     k_g13<false><<<2992, 256, 0, stream>>>(Xb, W1, W3, b1, b3, rowsL, cntP, offP, tabP, H1);

  if (wbf) k_gemm<0,true ,32><<<1408, 256, 0, stream>>>(Xb, ws+off_s1b, bs1, nullptr, Hs, nullptr,nullptr,nullptr,nullptr,nullptr);
  else     k_gemm<0,false,32><<<1408, 256, 0, stream>>>(Xb, Ws1, bs1, nullptr, Hs, nullptr,nullptr,nullptr,nullptr,nullptr);

  if (wbf) k_gemm<1,true ,44><<<1024, 256, 0, stream>>>(Hs, ws+off_s2b, bs2, out, nullptr, nullptr,nullptr,nullptr,nullptr,nullptr);
  else     k_gemm<1,false,44><<<1024, 256, 0, stream>>>(Hs, Ws2, bs2, out, nullptr, nullptr,nullptr,nullptr,nullptr,nullptr);

  // flat 4352 = 8 XCD * 16 ct * 34 slots
  if (comb){
    if (wbf) k_gemm<3,true ,22><<<4352, 256, 0, stream>>>(H1, ws+off_w2b, b2, nullptr, Yr, rowsL, rwL, cntP, offP, tabP);
    else     k_gemm<3,false,22><<<4352, 256, 0, stream>>>(H1, W2, b2, nullptr, Yr, rowsL, rwL, cntP, offP, tabP);
    k_comb<<<N_TOK, 256, 0, stream>>>(Yr, slotL, out);
  } else {
    if (wbf) k_gemm<2,true ,22><<<4352, 256, 0, stream>>>(H1, ws+off_w2b, b2, out, nullptr, rowsL, rwL, cntP, offP, tabP);
    else     k_gemm<2,false,22><<<4352, 256, 0, stream>>>(H1, W2, b2, out, nullptr, rowsL, rwL, cntP, offP, tabP);
  }
}